// Round 11
// baseline (467.026 us; speedup 1.0000x reference)
//
#include <hip/hip_runtime.h>
#include <math.h>

#define N_NODES 50000
#define N_EDGES 800000
#define IN_FEAT 128
#define HEADS   4
#define UNITS   16
#define OUTF    64          // HEADS*UNITS
#define LEAKY   0.2f

#define NB      196         // buckets: rcv>>8, 256 nodes each
#define BCAP    5120        // bucket capacity
#define GEMM_BLKS 782       // ceil(N_NODES/64)
#define A_BLOCKS  391       // ceil(N_EDGES/2048)
#define EPB     8           // edges per thread in phase A

typedef __attribute__((ext_vector_type(8))) short bf16x8;
typedef __attribute__((ext_vector_type(4))) float f32x4;

__device__ __forceinline__ unsigned short f2bf(float f) {
    unsigned u = __float_as_uint(f);
    unsigned r = u + 0x7FFFu + ((u >> 16) & 1u);   // RNE
    return (unsigned short)(r >> 16);
}

union SharedU {
    struct { unsigned short xl[64 * 136]; unsigned short wt[64 * 136]; } g; // 34816 B
    struct { int2 stage[2048]; int hist[256], s[256], excl[256],
             gbase[256], cur[256]; } a;                                     // 21504 B
};

// ---- one-time: W[k][c] fp32 -> Wt_g[c][k] bf16; block 0 zeros bucket_cnt ----
__global__ __launch_bounds__(256) void wt_prep(const float* __restrict__ W,
                                               unsigned short* __restrict__ Wt_g,
                                               int* __restrict__ bucket_cnt) {
    int idx = blockIdx.x * 256 + threadIdx.x;
    if (blockIdx.x == 0 && threadIdx.x < NB) bucket_cnt[threadIdx.x] = 0;
    if (idx < IN_FEAT * OUTF) {
        int k = idx >> 6, c = idx & 63;
        Wt_g[c * IN_FEAT + k] = f2bf(W[idx]);
    }
}

// ---- fused: [h = x@W (MFMA bf16) + att scalars] | [bucket scatter] ----
__global__ __launch_bounds__(256) void fused_gemm_bucketA(const float* __restrict__ x,
                                                          const unsigned short* __restrict__ Wt_g,
                                                          const float* __restrict__ w1,
                                                          const float* __restrict__ w2,
                                                          const int2* __restrict__ ei,
                                                          unsigned short* __restrict__ hg,
                                                          float* __restrict__ a1,
                                                          float* __restrict__ a2,
                                                          int* __restrict__ bucket_cnt,
                                                          int2* __restrict__ buckets) {
    __shared__ SharedU sh;
    const int t = threadIdx.x;

    if (blockIdx.x >= GEMM_BLKS) {
        // ---------------- phase A: bucket scatter with LDS reorder ----------
        const int e0 = (blockIdx.x - GEMM_BLKS) * 2048;
        sh.a.hist[t] = 0;
        __syncthreads();

        int2 ed[EPB]; int bk[EPB];
        #pragma unroll
        for (int j = 0; j < EPB; ++j) {
            int e = e0 + t + j * 256;
            if (e < N_EDGES) {
                ed[j] = ei[e];
                bk[j] = ed[j].y >> 8;
                atomicAdd(&sh.a.hist[bk[j]], 1);
            } else bk[j] = -1;
        }
        __syncthreads();
        int v = sh.a.hist[t];
        sh.a.s[t] = v;
        __syncthreads();
        #pragma unroll
        for (int off = 1; off < 256; off <<= 1) {
            int u = (t >= off) ? sh.a.s[t - off] : 0;
            __syncthreads();
            sh.a.s[t] += u;
            __syncthreads();
        }
        sh.a.excl[t] = sh.a.s[t] - v;
        sh.a.cur[t] = 0;
        if (t < NB) sh.a.gbase[t] = atomicAdd(&bucket_cnt[t], v);
        __syncthreads();
        #pragma unroll
        for (int j = 0; j < EPB; ++j) {
            if (bk[j] >= 0) {
                int p = sh.a.excl[bk[j]] + atomicAdd(&sh.a.cur[bk[j]], 1);
                sh.a.stage[p] = ed[j];
            }
        }
        __syncthreads();
        const int total = min(2048, N_EDGES - e0);
        for (int i = t; i < total; i += 256) {
            int2 vv = sh.a.stage[i];
            int b = vv.y >> 8;
            buckets[(size_t)b * BCAP + sh.a.gbase[b] + (i - sh.a.excl[b])] = vv;
        }
        return;
    }

    // ---------------- MFMA gemm: 64 nodes x 64 cols, 4 waves ----------------
    const int node0 = blockIdx.x * 64;
    unsigned short* xl = sh.g.xl;   // [64][136] bf16 (pad 8)
    unsigned short* wt = sh.g.wt;   // [64][136] bf16

    #pragma unroll
    for (int it = 0; it < 8; ++it) {
        int idx = t + 256 * it;
        int r = idx >> 5, q = idx & 31;
        int node = node0 + r;
        float4 v = make_float4(0.f, 0.f, 0.f, 0.f);
        if (node < N_NODES) v = *(const float4*)(x + (size_t)node * IN_FEAT + q * 4);
        ushort4 b;
        b.x = f2bf(v.x); b.y = f2bf(v.y); b.z = f2bf(v.z); b.w = f2bf(v.w);
        *(ushort4*)&xl[r * 136 + q * 4] = b;
    }
    {
        const ushort4* Wt4 = (const ushort4*)Wt_g;
        #pragma unroll
        for (int it = 0; it < 8; ++it) {
            int idx = t + 256 * it;
            int c = idx >> 5, u = idx & 31;
            *(ushort4*)&wt[c * 136 + u * 4] = Wt4[idx];
        }
    }
    __syncthreads();

    const int lane = t & 63, wv = t >> 6;
    const int m = lane & 15, quad = lane >> 4;
    const int n0 = wv * 16;                       // wave's 16-node slab

    f32x4 acc[4] = {{0,0,0,0},{0,0,0,0},{0,0,0,0},{0,0,0,0}};
    #pragma unroll
    for (int kc = 0; kc < 4; ++kc) {
        bf16x8 af = *(bf16x8*)&xl[(n0 + m) * 136 + kc * 32 + quad * 8];
        #pragma unroll
        for (int ct = 0; ct < 4; ++ct) {
            bf16x8 bfr = *(bf16x8*)&wt[(ct * 16 + m) * 136 + kc * 32 + quad * 8];
            acc[ct] = __builtin_amdgcn_mfma_f32_16x16x32_bf16(af, bfr, acc[ct], 0, 0, 0);
        }
    }

    // a1/a2 from fp32 accumulators: head == ct; reduce over 16 cols (lane&15)
    #pragma unroll
    for (int ct = 0; ct < 4; ++ct) {
        const float u1 = w1[ct * 16 + m];
        const float u2 = w2[ct * 16 + m];
        #pragma unroll
        for (int r = 0; r < 4; ++r) {
            float p1 = acc[ct][r] * u1;
            float p2 = acc[ct][r] * u2;
            p1 += __shfl_xor(p1, 1, 64); p1 += __shfl_xor(p1, 2, 64);
            p1 += __shfl_xor(p1, 4, 64); p1 += __shfl_xor(p1, 8, 64);
            p2 += __shfl_xor(p2, 1, 64); p2 += __shfl_xor(p2, 2, 64);
            p2 += __shfl_xor(p2, 4, 64); p2 += __shfl_xor(p2, 8, 64);
            if (m == 0) {
                int node = node0 + n0 + quad * 4 + r;
                if (node < N_NODES) {
                    a1[node * 4 + ct] = p1;
                    a2[node * 4 + ct] = p2;
                }
            }
        }
    }

    // h epilogue: C-layout -> LDS bf16 [64][72] -> coalesced uint4 stores
    __syncthreads();
    unsigned short* hl = sh.g.xl;                 // reuse: 64*72 = 4608 ushort
    #pragma unroll
    for (int ct = 0; ct < 4; ++ct)
        #pragma unroll
        for (int r = 0; r < 4; ++r)
            hl[(n0 + quad * 4 + r) * 72 + ct * 16 + m] = f2bf(acc[ct][r]);
    __syncthreads();
    #pragma unroll
    for (int it = 0; it < 2; ++it) {
        int u = t + 256 * it;                     // 512 units: 64 rows x 8 groups
        int r = u >> 3, cg = u & 7;               // each group = 8 cols (uint4)
        int node = node0 + r;
        if (node < N_NODES)
            *(uint4*)&hg[(size_t)node * OUTF + cg * 8] = *(uint4*)&hl[r * 72 + cg * 8];
    }
}

// ---- fused sort-free softmax+aggregation: block per bucket, LDS accum ----
// oacc: 256 node rows x 68 fp32 (pad 4); dsum: per (node, head) fp32.
__global__ __launch_bounds__(1024, 2) void gather_lds(const int2* __restrict__ buckets,
                                                      const int* __restrict__ bucket_cnt,
                                                      const float* __restrict__ a1,
                                                      const float* __restrict__ a2,
                                                      const unsigned short* __restrict__ h,
                                                      float* __restrict__ out) {
    __shared__ float oacc[256 * 68];   // 69632 B
    __shared__ float dsum[256 * 4];    // per (row, head)
    __shared__ float a2l[1024];
    const int b = blockIdx.x;
    const int t = threadIdx.x;
    const int cnt = bucket_cnt[b];

    for (int i = t; i < 256 * 68; i += 1024) oacc[i] = 0.f;
    dsum[t] = 0.f;
    {
        int gi = b * 1024 + t;
        a2l[t] = (gi < N_NODES * HEADS) ? a2[gi] : 0.f;
    }
    __syncthreads();

    const int lane = t & 63;
    const int wv   = t >> 6;           // 16 waves
    const int sub  = lane >> 3;        // edge slot 0..7
    const int li   = lane & 7;         // 8-col group
    const int head = li >> 1;
    const uint4* h4 = (const uint4*)h;
    const int2* bptr = buckets + (size_t)b * BCAP;

    for (int i = wv * 8 + sub; i < cnt; i += 128) {
        int2 ed = bptr[i];
        int row = ed.y & 255;
        float t0 = a1[ed.x * 4 + head] + a2l[row * 4 + head];
        t0 = t0 > 0.f ? t0 : LEAKY * t0;
        float e = __expf(t0);
        uint4 hv = h4[(unsigned)(ed.x * 8 + li)];
        const unsigned hw[4] = {hv.x, hv.y, hv.z, hv.w};
        float* orow = &oacc[row * 68 + li * 8];
        #pragma unroll
        for (int q = 0; q < 4; ++q) {
            atomicAdd(&orow[q * 2 + 0], e * __uint_as_float(hw[q] << 16));
            atomicAdd(&orow[q * 2 + 1], e * __uint_as_float(hw[q] & 0xFFFF0000u));
        }
        if ((li & 1) == 0) atomicAdd(&dsum[row * 4 + head], e);   // one add per head
    }
    __syncthreads();

    // epilogue: 256 rows x 16 float4 groups, coalesced; head of group g = g>>2
    for (int u = t; u < 256 * 16; u += 1024) {
        int r = u >> 4, g = u & 15;
        int node = b * 256 + r;
        if (node >= N_NODES) continue;
        float dv = dsum[r * 4 + (g >> 2)];
        float inv = dv > 0.f ? 1.f / dv : 0.f;
        const float* orow = &oacc[r * 68 + g * 4];
        *(float4*)(out + (size_t)node * OUTF + g * 4) =
            make_float4(orow[0] * inv, orow[1] * inv, orow[2] * inv, orow[3] * inv);
    }
}

extern "C" void kernel_launch(void* const* d_in, const int* in_sizes, int n_in,
                              void* d_out, int out_size, void* d_ws, size_t ws_size,
                              hipStream_t stream) {
    const float* x  = (const float*)d_in[0];
    const int2*  ei = (const int2*)d_in[1];
    const float* W  = (const float*)d_in[2];
    const float* w1 = (const float*)d_in[3];
    const float* w2 = (const float*)d_in[4];
    float* out = (float*)d_out;

    // workspace layout (bytes):
    // h bf16 6.4M | a1 0.8M | a2 0.8M | buckets 8.03M | bucket_cnt 784B | Wt_g 16K
    unsigned short* h = (unsigned short*)d_ws;
    float* a1         = (float*)(h + (size_t)N_NODES * OUTF);
    float* a2         = a1 + (size_t)N_NODES * HEADS;
    int2*  buckets    = (int2*)(a2 + (size_t)N_NODES * HEADS);
    int*   bucket_cnt = (int*)(buckets + (size_t)NB * BCAP);
    unsigned short* Wt_g = (unsigned short*)(bucket_cnt + NB);

    wt_prep<<<32, 256, 0, stream>>>(W, Wt_g, bucket_cnt);
    fused_gemm_bucketA<<<GEMM_BLKS + A_BLOCKS, 256, 0, stream>>>(x, Wt_g, w1, w2, ei,
                                                                 h, a1, a2,
                                                                 bucket_cnt, buckets);
    gather_lds<<<NB, 1024, 0, stream>>>(buckets, bucket_cnt, a1, a2, h, out);
}

// Round 13
// 466.393 us; speedup vs baseline: 1.0014x; 1.0014x over previous
//
#include <hip/hip_runtime.h>
#include <math.h>

#define N_NODES 50000
#define N_EDGES 800000
#define IN_FEAT 128
#define HEADS   4
#define UNITS   16
#define OUTF    64          // HEADS*UNITS
#define LEAKY   0.2f

#define NB      196         // buckets: rcv>>8, 256 nodes each
#define BCAP    5120        // bucket capacity
#define GEMM_BLKS 782       // ceil(N_NODES/64)
#define A_BLOCKS  391       // ceil(N_EDGES/2048)
#define EPB     8           // edges per thread in phase A

typedef __attribute__((ext_vector_type(8))) short bf16x8;
typedef __attribute__((ext_vector_type(4))) float f32x4;

__device__ __forceinline__ unsigned short f2bf(float f) {
    unsigned u = __float_as_uint(f);
    unsigned r = u + 0x7FFFu + ((u >> 16) & 1u);   // RNE
    return (unsigned short)(r >> 16);
}

// Native no-return LDS fp32 add. atomicAdd(float*) on a generic pointer
// compiles to a flat CAS loop (R11: 374 us + 20 ms contention outlier).
// Generic pointers to __shared__ carry the LDS byte offset in the low dword.
// CAVEAT (R12): the compiler does NOT track inline-asm DS ops in its waitcnt
// model -- an explicit s_waitcnt lgkmcnt(0) is required before any barrier
// that must observe these adds (see lds_drain()).
__device__ __forceinline__ void lds_fadd(float* p, float v) {
    unsigned off = (unsigned)(unsigned long long)p;
    asm volatile("ds_add_f32 %0, %1" :: "v"(off), "v"(v) : "memory");
}
__device__ __forceinline__ void lds_drain() {
    asm volatile("s_waitcnt lgkmcnt(0)" ::: "memory");
}

union SharedU {
    struct { unsigned short xl[64 * 136]; unsigned short wt[64 * 136]; } g; // 34816 B
    struct { int2 stage[2048]; int hist[256], s[256], excl[256],
             gbase[256], cur[256]; } a;                                     // 21504 B
};

// ---- one-time: W[k][c] fp32 -> Wt_g[c][k] bf16; block 0 zeros bucket_cnt ----
__global__ __launch_bounds__(256) void wt_prep(const float* __restrict__ W,
                                               unsigned short* __restrict__ Wt_g,
                                               int* __restrict__ bucket_cnt) {
    int idx = blockIdx.x * 256 + threadIdx.x;
    if (blockIdx.x == 0 && threadIdx.x < NB) bucket_cnt[threadIdx.x] = 0;
    if (idx < IN_FEAT * OUTF) {
        int k = idx >> 6, c = idx & 63;
        Wt_g[c * IN_FEAT + k] = f2bf(W[idx]);
    }
}

// ---- fused: [h = x@W (MFMA bf16) + att scalars] | [bucket scatter] ----
__global__ __launch_bounds__(256) void fused_gemm_bucketA(const float* __restrict__ x,
                                                          const unsigned short* __restrict__ Wt_g,
                                                          const float* __restrict__ w1,
                                                          const float* __restrict__ w2,
                                                          const int2* __restrict__ ei,
                                                          unsigned short* __restrict__ hg,
                                                          float* __restrict__ a1,
                                                          float* __restrict__ a2,
                                                          int* __restrict__ bucket_cnt,
                                                          int2* __restrict__ buckets) {
    __shared__ SharedU sh;
    const int t = threadIdx.x;

    if (blockIdx.x >= GEMM_BLKS) {
        // ---------------- phase A: bucket scatter with LDS reorder ----------
        const int e0 = (blockIdx.x - GEMM_BLKS) * 2048;
        sh.a.hist[t] = 0;
        __syncthreads();

        int2 ed[EPB]; int bk[EPB];
        #pragma unroll
        for (int j = 0; j < EPB; ++j) {
            int e = e0 + t + j * 256;
            if (e < N_EDGES) {
                ed[j] = ei[e];
                bk[j] = ed[j].y >> 8;
                atomicAdd(&sh.a.hist[bk[j]], 1);
            } else bk[j] = -1;
        }
        __syncthreads();
        int v = sh.a.hist[t];
        sh.a.s[t] = v;
        __syncthreads();
        #pragma unroll
        for (int off = 1; off < 256; off <<= 1) {
            int u = (t >= off) ? sh.a.s[t - off] : 0;
            __syncthreads();
            sh.a.s[t] += u;
            __syncthreads();
        }
        sh.a.excl[t] = sh.a.s[t] - v;
        sh.a.cur[t] = 0;
        if (t < NB) sh.a.gbase[t] = atomicAdd(&bucket_cnt[t], v);
        __syncthreads();
        #pragma unroll
        for (int j = 0; j < EPB; ++j) {
            if (bk[j] >= 0) {
                int p = sh.a.excl[bk[j]] + atomicAdd(&sh.a.cur[bk[j]], 1);
                sh.a.stage[p] = ed[j];
            }
        }
        __syncthreads();
        const int total = min(2048, N_EDGES - e0);
        for (int i = t; i < total; i += 256) {
            int2 vv = sh.a.stage[i];
            int b = vv.y >> 8;
            buckets[(size_t)b * BCAP + sh.a.gbase[b] + (i - sh.a.excl[b])] = vv;
        }
        return;
    }

    // ---------------- MFMA gemm: 64 nodes x 64 cols, 4 waves ----------------
    const int node0 = blockIdx.x * 64;
    unsigned short* xl = sh.g.xl;   // [64][136] bf16 (pad 8)
    unsigned short* wt = sh.g.wt;   // [64][136] bf16

    #pragma unroll
    for (int it = 0; it < 8; ++it) {
        int idx = t + 256 * it;
        int r = idx >> 5, q = idx & 31;
        int node = node0 + r;
        float4 v = make_float4(0.f, 0.f, 0.f, 0.f);
        if (node < N_NODES) v = *(const float4*)(x + (size_t)node * IN_FEAT + q * 4);
        ushort4 b;
        b.x = f2bf(v.x); b.y = f2bf(v.y); b.z = f2bf(v.z); b.w = f2bf(v.w);
        *(ushort4*)&xl[r * 136 + q * 4] = b;
    }
    {
        const ushort4* Wt4 = (const ushort4*)Wt_g;
        #pragma unroll
        for (int it = 0; it < 8; ++it) {
            int idx = t + 256 * it;
            int c = idx >> 5, u = idx & 31;
            *(ushort4*)&wt[c * 136 + u * 4] = Wt4[idx];
        }
    }
    __syncthreads();

    const int lane = t & 63, wv = t >> 6;
    const int m = lane & 15, quad = lane >> 4;
    const int n0 = wv * 16;                       // wave's 16-node slab

    f32x4 acc[4] = {{0,0,0,0},{0,0,0,0},{0,0,0,0},{0,0,0,0}};
    #pragma unroll
    for (int kc = 0; kc < 4; ++kc) {
        bf16x8 af = *(bf16x8*)&xl[(n0 + m) * 136 + kc * 32 + quad * 8];
        #pragma unroll
        for (int ct = 0; ct < 4; ++ct) {
            bf16x8 bfr = *(bf16x8*)&wt[(ct * 16 + m) * 136 + kc * 32 + quad * 8];
            acc[ct] = __builtin_amdgcn_mfma_f32_16x16x32_bf16(af, bfr, acc[ct], 0, 0, 0);
        }
    }

    // a1/a2 from fp32 accumulators: head == ct; reduce over 16 cols (lane&15)
    #pragma unroll
    for (int ct = 0; ct < 4; ++ct) {
        const float u1 = w1[ct * 16 + m];
        const float u2 = w2[ct * 16 + m];
        #pragma unroll
        for (int r = 0; r < 4; ++r) {
            float p1 = acc[ct][r] * u1;
            float p2 = acc[ct][r] * u2;
            p1 += __shfl_xor(p1, 1, 64); p1 += __shfl_xor(p1, 2, 64);
            p1 += __shfl_xor(p1, 4, 64); p1 += __shfl_xor(p1, 8, 64);
            p2 += __shfl_xor(p2, 1, 64); p2 += __shfl_xor(p2, 2, 64);
            p2 += __shfl_xor(p2, 4, 64); p2 += __shfl_xor(p2, 8, 64);
            if (m == 0) {
                int node = node0 + n0 + quad * 4 + r;
                if (node < N_NODES) {
                    a1[node * 4 + ct] = p1;
                    a2[node * 4 + ct] = p2;
                }
            }
        }
    }

    // h epilogue: C-layout -> LDS bf16 [64][72] -> coalesced uint4 stores
    __syncthreads();
    unsigned short* hl = sh.g.xl;                 // reuse: 64*72 = 4608 ushort
    #pragma unroll
    for (int ct = 0; ct < 4; ++ct)
        #pragma unroll
        for (int r = 0; r < 4; ++r)
            hl[(n0 + quad * 4 + r) * 72 + ct * 16 + m] = f2bf(acc[ct][r]);
    __syncthreads();
    #pragma unroll
    for (int it = 0; it < 2; ++it) {
        int u = t + 256 * it;                     // 512 units: 64 rows x 8 groups
        int r = u >> 3, cg = u & 7;               // each group = 8 cols (uint4)
        int node = node0 + r;
        if (node < N_NODES)
            *(uint4*)&hg[(size_t)node * OUTF + cg * 8] = *(uint4*)&hl[r * 72 + cg * 8];
    }
}

// ---- fused sort-free softmax+aggregation: block per bucket, LDS accum ----
// oacc: 256 node rows x 68 fp32 (pad 4); dsum: per (node, head) fp32.
// Accumulation via native ds_add_f32; MUST drain lgkmcnt explicitly before
// the barrier (compiler can't see asm DS ops -- R12 failed without it).
__global__ __launch_bounds__(1024, 2) void gather_lds(const int2* __restrict__ buckets,
                                                      const int* __restrict__ bucket_cnt,
                                                      const float* __restrict__ a1,
                                                      const float* __restrict__ a2,
                                                      const unsigned short* __restrict__ h,
                                                      float* __restrict__ out) {
    __shared__ float oacc[256 * 68];   // 69632 B
    __shared__ float dsum[256 * 4];    // per (row, head)
    __shared__ float a2l[1024];
    const int b = blockIdx.x;
    const int t = threadIdx.x;
    const int cnt = bucket_cnt[b];

    for (int i = t; i < 256 * 68; i += 1024) oacc[i] = 0.f;
    dsum[t] = 0.f;
    {
        int gi = b * 1024 + t;
        a2l[t] = (gi < N_NODES * HEADS) ? a2[gi] : 0.f;
    }
    __syncthreads();

    const int lane = t & 63;
    const int wv   = t >> 6;           // 16 waves
    const int sub  = lane >> 3;        // edge slot 0..7
    const int li   = lane & 7;         // 8-col group
    const int head = li >> 1;
    const uint4* h4 = (const uint4*)h;
    const int2* bptr = buckets + (size_t)b * BCAP;

    for (int i = wv * 8 + sub; i < cnt; i += 128) {
        int2 ed = bptr[i];
        int row = ed.y & 255;
        float t0 = a1[ed.x * 4 + head] + a2l[row * 4 + head];
        t0 = t0 > 0.f ? t0 : LEAKY * t0;
        float e = __expf(t0);
        uint4 hv = h4[(unsigned)(ed.x * 8 + li)];
        const unsigned hw[4] = {hv.x, hv.y, hv.z, hv.w};
        float* orow = &oacc[row * 68 + li * 8];
        #pragma unroll
        for (int q = 0; q < 4; ++q) {
            lds_fadd(&orow[q * 2 + 0], e * __uint_as_float(hw[q] << 16));
            lds_fadd(&orow[q * 2 + 1], e * __uint_as_float(hw[q] & 0xFFFF0000u));
        }
        if ((li & 1) == 0) lds_fadd(&dsum[row * 4 + head], e);    // one add per head
    }
    lds_drain();            // drain asm ds_add_f32 before the barrier (R12 bug)
    __syncthreads();

    // epilogue: 256 rows x 16 float4 groups, coalesced; head of group g = g>>2
    for (int u = t; u < 256 * 16; u += 1024) {
        int r = u >> 4, g = u & 15;
        int node = b * 256 + r;
        if (node >= N_NODES) continue;
        float dv = dsum[r * 4 + (g >> 2)];
        float inv = dv > 0.f ? 1.f / dv : 0.f;
        const float* orow = &oacc[r * 68 + g * 4];
        *(float4*)(out + (size_t)node * OUTF + g * 4) =
            make_float4(orow[0] * inv, orow[1] * inv, orow[2] * inv, orow[3] * inv);
    }
}

extern "C" void kernel_launch(void* const* d_in, const int* in_sizes, int n_in,
                              void* d_out, int out_size, void* d_ws, size_t ws_size,
                              hipStream_t stream) {
    const float* x  = (const float*)d_in[0];
    const int2*  ei = (const int2*)d_in[1];
    const float* W  = (const float*)d_in[2];
    const float* w1 = (const float*)d_in[3];
    const float* w2 = (const float*)d_in[4];
    float* out = (float*)d_out;

    // workspace layout (bytes):
    // h bf16 6.4M | a1 0.8M | a2 0.8M | buckets 8.03M | bucket_cnt 784B | Wt_g 16K
    unsigned short* h = (unsigned short*)d_ws;
    float* a1         = (float*)(h + (size_t)N_NODES * OUTF);
    float* a2         = a1 + (size_t)N_NODES * HEADS;
    int2*  buckets    = (int2*)(a2 + (size_t)N_NODES * HEADS);
    int*   bucket_cnt = (int*)(buckets + (size_t)NB * BCAP);
    unsigned short* Wt_g = (unsigned short*)(bucket_cnt + NB);

    wt_prep<<<32, 256, 0, stream>>>(W, Wt_g, bucket_cnt);
    fused_gemm_bucketA<<<GEMM_BLKS + A_BLOCKS, 256, 0, stream>>>(x, Wt_g, w1, w2, ei,
                                                                 h, a1, a2,
                                                                 bucket_cnt, buckets);
    gather_lds<<<NB, 1024, 0, stream>>>(buckets, bucket_cnt, a1, a2, h, out);
}

// Round 14
// 141.114 us; speedup vs baseline: 3.3096x; 3.3051x over previous
//
#include <hip/hip_runtime.h>
#include <math.h>

#define N_NODES 50000
#define N_EDGES 800000
#define IN_FEAT 128
#define HEADS   4
#define UNITS   16
#define OUTF    64          // HEADS*UNITS
#define LEAKY   0.2f

#define NB      196         // buckets: rcv>>8, 256 nodes each
#define BCAP    5120        // bucket capacity
#define GEMM_BLKS 782       // ceil(N_NODES/64)
#define A_BLOCKS  391       // ceil(N_EDGES/2048)
#define EPB     8           // edges per thread in phase A

typedef __attribute__((ext_vector_type(8))) short bf16x8;
typedef __attribute__((ext_vector_type(4))) float f32x4;

__device__ __forceinline__ unsigned short f2bf(float f) {
    unsigned u = __float_as_uint(f);
    unsigned r = u + 0x7FFFu + ((u >> 16) & 1u);   // RNE
    return (unsigned short)(r >> 16);
}

union SharedU {
    struct { unsigned short xl[64 * 136]; unsigned short wt[64 * 136]; } g; // 34816 B
    struct { int2 stage[2048]; int hist[256], s[256], excl[256],
             gbase[256], cur[256]; } a;                                     // 21504 B
};

// ---- one-time: W[k][c] fp32 -> Wt_g[c][k] bf16; block 0 zeros bucket_cnt ----
__global__ __launch_bounds__(256) void wt_prep(const float* __restrict__ W,
                                               unsigned short* __restrict__ Wt_g,
                                               int* __restrict__ bucket_cnt) {
    int idx = blockIdx.x * 256 + threadIdx.x;
    if (blockIdx.x == 0 && threadIdx.x < NB) bucket_cnt[threadIdx.x] = 0;
    if (idx < IN_FEAT * OUTF) {
        int k = idx >> 6, c = idx & 63;
        Wt_g[c * IN_FEAT + k] = f2bf(W[idx]);
    }
}

// ---- fused: [h = x@W (MFMA bf16) + att scalars] | [bucket scatter] ----
__global__ __launch_bounds__(256) void fused_gemm_bucketA(const float* __restrict__ x,
                                                          const unsigned short* __restrict__ Wt_g,
                                                          const float* __restrict__ w1,
                                                          const float* __restrict__ w2,
                                                          const int2* __restrict__ ei,
                                                          unsigned short* __restrict__ hg,
                                                          float* __restrict__ a1,
                                                          float* __restrict__ a2,
                                                          int* __restrict__ bucket_cnt,
                                                          int2* __restrict__ buckets) {
    __shared__ SharedU sh;
    const int t = threadIdx.x;

    if (blockIdx.x >= GEMM_BLKS) {
        // ---------------- phase A: bucket scatter with LDS reorder ----------
        const int e0 = (blockIdx.x - GEMM_BLKS) * 2048;
        sh.a.hist[t] = 0;
        __syncthreads();

        int2 ed[EPB]; int bk[EPB];
        #pragma unroll
        for (int j = 0; j < EPB; ++j) {
            int e = e0 + t + j * 256;
            if (e < N_EDGES) {
                ed[j] = ei[e];
                bk[j] = ed[j].y >> 8;
                atomicAdd(&sh.a.hist[bk[j]], 1);
            } else bk[j] = -1;
        }
        __syncthreads();
        int v = sh.a.hist[t];
        sh.a.s[t] = v;
        __syncthreads();
        #pragma unroll
        for (int off = 1; off < 256; off <<= 1) {
            int u = (t >= off) ? sh.a.s[t - off] : 0;
            __syncthreads();
            sh.a.s[t] += u;
            __syncthreads();
        }
        sh.a.excl[t] = sh.a.s[t] - v;
        sh.a.cur[t] = 0;
        if (t < NB) sh.a.gbase[t] = atomicAdd(&bucket_cnt[t], v);
        __syncthreads();
        #pragma unroll
        for (int j = 0; j < EPB; ++j) {
            if (bk[j] >= 0) {
                int p = sh.a.excl[bk[j]] + atomicAdd(&sh.a.cur[bk[j]], 1);
                sh.a.stage[p] = ed[j];
            }
        }
        __syncthreads();
        const int total = min(2048, N_EDGES - e0);
        for (int i = t; i < total; i += 256) {
            int2 vv = sh.a.stage[i];
            int b = vv.y >> 8;
            buckets[(size_t)b * BCAP + sh.a.gbase[b] + (i - sh.a.excl[b])] = vv;
        }
        return;
    }

    // ---------------- MFMA gemm: 64 nodes x 64 cols, 4 waves ----------------
    const int node0 = blockIdx.x * 64;
    unsigned short* xl = sh.g.xl;   // [64][136] bf16 (pad 8)
    unsigned short* wt = sh.g.wt;   // [64][136] bf16

    #pragma unroll
    for (int it = 0; it < 8; ++it) {
        int idx = t + 256 * it;
        int r = idx >> 5, q = idx & 31;
        int node = node0 + r;
        float4 v = make_float4(0.f, 0.f, 0.f, 0.f);
        if (node < N_NODES) v = *(const float4*)(x + (size_t)node * IN_FEAT + q * 4);
        ushort4 b;
        b.x = f2bf(v.x); b.y = f2bf(v.y); b.z = f2bf(v.z); b.w = f2bf(v.w);
        *(ushort4*)&xl[r * 136 + q * 4] = b;
    }
    {
        const ushort4* Wt4 = (const ushort4*)Wt_g;
        #pragma unroll
        for (int it = 0; it < 8; ++it) {
            int idx = t + 256 * it;
            int c = idx >> 5, u = idx & 31;
            *(ushort4*)&wt[c * 136 + u * 4] = Wt4[idx];
        }
    }
    __syncthreads();

    const int lane = t & 63, wv = t >> 6;
    const int m = lane & 15, quad = lane >> 4;
    const int n0 = wv * 16;                       // wave's 16-node slab

    f32x4 acc[4] = {{0,0,0,0},{0,0,0,0},{0,0,0,0},{0,0,0,0}};
    #pragma unroll
    for (int kc = 0; kc < 4; ++kc) {
        bf16x8 af = *(bf16x8*)&xl[(n0 + m) * 136 + kc * 32 + quad * 8];
        #pragma unroll
        for (int ct = 0; ct < 4; ++ct) {
            bf16x8 bfr = *(bf16x8*)&wt[(ct * 16 + m) * 136 + kc * 32 + quad * 8];
            acc[ct] = __builtin_amdgcn_mfma_f32_16x16x32_bf16(af, bfr, acc[ct], 0, 0, 0);
        }
    }

    // a1/a2 from fp32 accumulators: head == ct; reduce over 16 cols (lane&15)
    #pragma unroll
    for (int ct = 0; ct < 4; ++ct) {
        const float u1 = w1[ct * 16 + m];
        const float u2 = w2[ct * 16 + m];
        #pragma unroll
        for (int r = 0; r < 4; ++r) {
            float p1 = acc[ct][r] * u1;
            float p2 = acc[ct][r] * u2;
            p1 += __shfl_xor(p1, 1, 64); p1 += __shfl_xor(p1, 2, 64);
            p1 += __shfl_xor(p1, 4, 64); p1 += __shfl_xor(p1, 8, 64);
            p2 += __shfl_xor(p2, 1, 64); p2 += __shfl_xor(p2, 2, 64);
            p2 += __shfl_xor(p2, 4, 64); p2 += __shfl_xor(p2, 8, 64);
            if (m == 0) {
                int node = node0 + n0 + quad * 4 + r;
                if (node < N_NODES) {
                    a1[node * 4 + ct] = p1;
                    a2[node * 4 + ct] = p2;
                }
            }
        }
    }

    // h epilogue: C-layout -> LDS bf16 [64][72] -> coalesced uint4 stores
    __syncthreads();
    unsigned short* hl = sh.g.xl;                 // reuse: 64*72 = 4608 ushort
    #pragma unroll
    for (int ct = 0; ct < 4; ++ct)
        #pragma unroll
        for (int r = 0; r < 4; ++r)
            hl[(n0 + quad * 4 + r) * 72 + ct * 16 + m] = f2bf(acc[ct][r]);
    __syncthreads();
    #pragma unroll
    for (int it = 0; it < 2; ++it) {
        int u = t + 256 * it;                     // 512 units: 64 rows x 8 groups
        int r = u >> 3, cg = u & 7;               // each group = 8 cols (uint4)
        int node = node0 + r;
        if (node < N_NODES)
            *(uint4*)&hg[(size_t)node * OUTF + cg * 8] = *(uint4*)&hl[r * 72 + cg * 8];
    }
}

// ---- merged: per-bucket LDS counting sort + R9-style register gather ----
// Sort bucket edges into snds[] (LDS, by rcv&255), then each of 16 waves
// gathers 16 nodes with the 8-slot x uint4 inner loop (edge ids from LDS).
// No fp32 LDS atomics anywhere (R11/R13 lesson); int LDS atomics are native.
__global__ __launch_bounds__(1024) void sort_gather(const int2* __restrict__ buckets,
                                                    const int* __restrict__ bucket_cnt,
                                                    const float* __restrict__ a1,
                                                    const float* __restrict__ a2,
                                                    const unsigned short* __restrict__ h,
                                                    float* __restrict__ out) {
    __shared__ int snds[BCAP];                 // 20480 B
    __shared__ int hist[256], cur[256], rowbeg[256], sarr[256];
    __shared__ float a2l[1024];
    const int b = blockIdx.x;
    const int t = threadIdx.x;
    const int cnt = bucket_cnt[b];
    const int2* bptr = buckets + (size_t)b * BCAP;

    if (t < 256) hist[t] = 0;
    {
        int gi = b * 1024 + t;
        a2l[t] = (gi < N_NODES * HEADS) ? a2[gi] : 0.f;
    }
    __syncthreads();

    // histogram by rcv&255
    for (int i = t; i < cnt; i += 1024) atomicAdd(&hist[bptr[i].y & 255], 1);
    __syncthreads();

    // exclusive scan of 256 counts (threads t<256; barriers block-wide)
    int v = 0;
    if (t < 256) { v = hist[t]; sarr[t] = v; }
    __syncthreads();
    #pragma unroll
    for (int off = 1; off < 256; off <<= 1) {
        int u = 0;
        if (t < 256 && t >= off) u = sarr[t - off];
        __syncthreads();
        if (t < 256) sarr[t] += u;
        __syncthreads();
    }
    if (t < 256) { rowbeg[t] = sarr[t] - v; cur[t] = sarr[t] - v; }
    __syncthreads();

    // scatter sender ids into sorted LDS slots
    for (int i = t; i < cnt; i += 1024) {
        int2 ed = bptr[i];
        int p = atomicAdd(&cur[ed.y & 255], 1);
        snds[p] = ed.x;
    }
    __syncthreads();

    // gather: wave wv handles nodes wv*16..wv*16+15
    const int lane = t & 63;
    const int wv   = t >> 6;                   // 16 waves
    const int sub  = lane >> 3;                // edge slot 0..7
    const int li   = lane & 7;                 // 8-col group
    const int head = li >> 1;
    const uint4* h4 = (const uint4*)h;

    for (int k = 0; k < 16; ++k) {
        const int r = wv * 16 + k;
        const int node = b * 256 + r;
        if (node >= N_NODES) break;
        const int beg = rowbeg[r];
        const int num = hist[r];
        const float a2h = a2l[r * 4 + head];

        float acc[8] = {0.f,0.f,0.f,0.f,0.f,0.f,0.f,0.f};
        float den = 0.f;

        for (int i0 = 0; i0 < num; i0 += 16) {
            #pragma unroll
            for (int g = 0; g < 2; ++g) {
                int idx = i0 + g * 8 + sub;
                int j = min(idx, num - 1);
                int s = snds[beg + j];         // LDS broadcast read
                float t0 = a1[s * 4 + head] + a2h;
                t0 = t0 > 0.f ? t0 : LEAKY * t0;
                float e = (idx < num) ? __expf(t0) : 0.f;
                uint4 hv = h4[(unsigned)(s * 8 + li)];
                const unsigned hw[4] = {hv.x, hv.y, hv.z, hv.w};
                #pragma unroll
                for (int q = 0; q < 4; ++q) {
                    acc[q*2+0] = fmaf(e, __uint_as_float(hw[q] << 16),         acc[q*2+0]);
                    acc[q*2+1] = fmaf(e, __uint_as_float(hw[q] & 0xFFFF0000u), acc[q*2+1]);
                }
                den += e;
            }
        }

        #pragma unroll
        for (int off = 8; off <= 32; off <<= 1) {
            #pragma unroll
            for (int q = 0; q < 8; ++q) acc[q] += __shfl_xor(acc[q], off, 64);
            den += __shfl_xor(den, off, 64);
        }

        if (sub == 0) {
            float inv = (num > 0) ? 1.f / den : 0.f;
            *(float4*)(out + (size_t)node * OUTF + li * 8) =
                make_float4(acc[0] * inv, acc[1] * inv, acc[2] * inv, acc[3] * inv);
            *(float4*)(out + (size_t)node * OUTF + li * 8 + 4) =
                make_float4(acc[4] * inv, acc[5] * inv, acc[6] * inv, acc[7] * inv);
        }
    }
}

extern "C" void kernel_launch(void* const* d_in, const int* in_sizes, int n_in,
                              void* d_out, int out_size, void* d_ws, size_t ws_size,
                              hipStream_t stream) {
    const float* x  = (const float*)d_in[0];
    const int2*  ei = (const int2*)d_in[1];
    const float* W  = (const float*)d_in[2];
    const float* w1 = (const float*)d_in[3];
    const float* w2 = (const float*)d_in[4];
    float* out = (float*)d_out;

    // workspace layout (bytes):
    // h bf16 6.4M | a1 0.8M | a2 0.8M | buckets 8.03M | bucket_cnt 784B | Wt_g 16K
    unsigned short* h = (unsigned short*)d_ws;
    float* a1         = (float*)(h + (size_t)N_NODES * OUTF);
    float* a2         = a1 + (size_t)N_NODES * HEADS;
    int2*  buckets    = (int2*)(a2 + (size_t)N_NODES * HEADS);
    int*   bucket_cnt = (int*)(buckets + (size_t)NB * BCAP);
    unsigned short* Wt_g = (unsigned short*)(bucket_cnt + NB);

    wt_prep<<<32, 256, 0, stream>>>(W, Wt_g, bucket_cnt);
    fused_gemm_bucketA<<<GEMM_BLKS + A_BLOCKS, 256, 0, stream>>>(x, Wt_g, w1, w2, ei,
                                                                 h, a1, a2,
                                                                 bucket_cnt, buckets);
    sort_gather<<<NB, 1024, 0, stream>>>(buckets, bucket_cnt, a1, a2, h, out);
}